// Round 1
// 337.750 us; speedup vs baseline: 1.7078x; 1.7078x over previous
//
#include <hip/hip_runtime.h>
#include <math.h>
#include <stdint.h>

#define B_ 32
#define N_ 1024
#define D_ 256
#define K_ 8
#define CAND 12

typedef unsigned short u16;
typedef unsigned int u32;
typedef __attribute__((ext_vector_type(8))) short s16x8;   // 8 bf16 (4 VGPRs)
typedef __attribute__((ext_vector_type(16))) float f32x16; // 32x32 accumulator

__device__ inline void cp16(const void* g, void* l) {
    // async global->LDS, 16B/lane; LDS dest = wave-uniform base + lane*16
    __builtin_amdgcn_global_load_lds((const __attribute__((address_space(1))) void*)g,
                                     (__attribute__((address_space(3))) void*)l, 16, 0, 0);
}

__device__ inline u16 f2bf(float f) {               // RNE float->bf16 bits
    uint32_t u = __float_as_uint(f);
    return (u16)((u + 0x7fffu + ((u >> 16) & 1u)) >> 16);
}
__device__ inline float bf2f(u16 h) { return __uint_as_float(((uint32_t)h) << 16); }
__device__ inline u32 umax32(u32 a, u32 b) { return a > b ? a : b; }
__device__ inline u32 umin32(u32 a, u32 b) { return a < b ? a : b; }

// ------------- Kernel 1: fp64 inverse norms + normalized bf16 hi/lo -------------
__global__ __launch_bounds__(256) void prep_kernel(const float* __restrict__ tok,
                                                   double* __restrict__ invn,
                                                   u16* __restrict__ xhi,
                                                   u16* __restrict__ xlo) {
    const int tid = threadIdx.x;
    const int wave = tid >> 6, lane = tid & 63;
    const int row = blockIdx.x * 4 + wave;          // 32768 rows
    const float4 v = *reinterpret_cast<const float4*>(tok + (size_t)row * D_ + lane * 4);
    double s = (double)v.x * v.x + (double)v.y * v.y +
               (double)v.z * v.z + (double)v.w * v.w;
    #pragma unroll
    for (int off = 32; off > 0; off >>= 1) s += __shfl_xor(s, off, 64);
    const double inv = 1.0 / (sqrt(s) + 1e-8);
    if (lane == 0) invn[row] = inv;
    const float x0 = (float)(v.x * inv), x1 = (float)(v.y * inv),
                x2 = (float)(v.z * inv), x3 = (float)(v.w * inv);
    ushort4 h, l;
    h.x = f2bf(x0); l.x = f2bf(x0 - bf2f(h.x));
    h.y = f2bf(x1); l.y = f2bf(x1 - bf2f(h.y));
    h.z = f2bf(x2); l.z = f2bf(x2 - bf2f(h.z));
    h.w = f2bf(x3); l.w = f2bf(x3 - bf2f(h.w));
    *reinterpret_cast<ushort4*>(xhi + (size_t)row * D_ + lane * 4) = h;
    *reinterpret_cast<ushort4*>(xlo + (size_t)row * D_ + lane * 4) = l;
}

// ------------- Kernel 2: MFMA sim + in-register packed-key top-12 + fp64 rescore ----
// Swapped MFMA operands: acc = mfma(B_frag, A_frag) so that
//   lane-dim (col=lane&31) <-> i-row, reg-dim <-> j: each lane holds 16 j-candidates
//   of ONE i-row per jt tile -> top-K scan stays in registers (no Sim LDS round-trip).
// C/D layout [m74/m101]: col=lane&31 (<-i), row=(reg&3)+8*(reg>>2)+4*(lane>>5) (<-j local).
// Key pack: top-24 bits = monotone fp32 bits, low 8 bits = (jt<<4)|reg; insert via
//   branchless v_max_u32/v_min_u32 sorted chain. fp64 rescore re-ranks exactly.
// Per row, candidates split over 4 slots: s = nq*2 + half (two nq-waves x two lane halves).
// LDS carve (48128 B -> 3 blocks/CU):
//   [0,32768)      Ah/Al/Bh/Bl tiles, 8KB each: [64 rows][8 x 16B chunks], XOR-swizzled
//   [32768,45056)  keysL [64 rows][4 slots][12] u32
//   [45056,48128)  mj [64][12] int
//   dv[64][12] double aliases tiles (dead after scan)
__global__ __launch_bounds__(256) void sim_topk_kernel(const u16* __restrict__ Xhi,
                                                       const u16* __restrict__ Xlo,
                                                       const float* __restrict__ tok,
                                                       const double* __restrict__ invn,
                                                       int* __restrict__ topk) {
    __shared__ __align__(16) char smem[48128];
    char* tiles = smem;
    u32*    keysL = (u32*)(smem + 32768);
    int*    mj    = (int*)(smem + 45056);
    double* dv    = (double*)smem;

    // XCD batch-affinity swizzle: consecutive ids round-robin XCDs [m09];
    // give each XCD 4 whole batches so the B panel (1MB hi+lo) stays in its L2.
    const int id    = blockIdx.x;            // 0..511
    const int chunk = id >> 3;               // 0..63
    const int b  = (id & 7) * 4 + (chunk >> 4);
    const int i0 = (chunk & 15) * 64;

    const int tid = threadIdx.x;
    const int w = tid >> 6, lane = tid & 63;
    const int mq = w >> 1, nq = w & 1;       // 2x2 wave grid of 32x32 tiles
    const int half = lane >> 5;
    const int il = lane & 31;

    const u16* XhiB = Xhi + (size_t)b * N_ * D_;
    const u16* XloB = Xlo + (size_t)b * N_ * D_;

    // staging role: wave 0->Ah, 1->Al, 2->Bh, 3->Bl (8 x 1KB cp16 each per stage)
    const u16* ssrc = (w & 1) ? XloB : XhiB;
    char* sdst = tiles + w * 8192;
    const int isA = (w < 2);
    const int srr = lane >> 3, spp = lane & 7;      // row-in-group, chunk-pos
    const int scs = spp ^ srr;                      // swizzle source chunk (r&7 == srr)

    // fragment rows (fixed per lane)
    const int ra = mq * 32 + il;
    const int rb = nq * 32 + il;
    const int xa = ra & 7, xb = rb & 7;             // XOR keys

    const int diag_jt = i0 >> 6;                    // jt where j-tile == i-strip

    u32 keys[CAND];
    #pragma unroll
    for (int c = 0; c < CAND; ++c) keys[c] = 0u;    // real sims always pack > 0

    for (int jt = 0; jt < 16; ++jt) {
        const int j0 = jt * 64;
        f32x16 acc;
        #pragma unroll
        for (int c = 0; c < 16; ++c) acc[c] = 0.0f;

        for (int kc = 0; kc < 4; ++kc) {
            const int k0 = kc * 64;
            __syncthreads();                        // tiles free for overwrite
            const int rowbase = isA ? i0 : j0;
            #pragma unroll
            for (int t = 0; t < 8; ++t) {
                const int r = t * 8 + srr;
                cp16(ssrc + (size_t)(rowbase + r) * D_ + k0 + scs * 8, sdst + t * 1024);
            }
            __syncthreads();                        // drain vmcnt + barrier
            #pragma unroll
            for (int ks = 0; ks < 4; ++ks) {
                const int ca = ((ks * 2 + half) ^ xa) * 16;
                const int cb = ((ks * 2 + half) ^ xb) * 16;
                const s16x8 ah = *(const s16x8*)(tiles +         ra * 128 + ca);
                const s16x8 al = *(const s16x8*)(tiles +  8192 + ra * 128 + ca);
                const s16x8 bh = *(const s16x8*)(tiles + 16384 + rb * 128 + cb);
                const s16x8 bl = *(const s16x8*)(tiles + 24576 + rb * 128 + cb);
                // swapped operands: reg-dim <-> j (b-rows), lane-dim <-> i (a-rows)
                acc = __builtin_amdgcn_mfma_f32_32x32x16_bf16(bh, ah, acc, 0, 0, 0);
                acc = __builtin_amdgcn_mfma_f32_32x32x16_bf16(bl, ah, acc, 0, 0, 0);
                acc = __builtin_amdgcn_mfma_f32_32x32x16_bf16(bh, al, acc, 0, 0, 0);
            }
        }

        // in-register scan: 16 j-candidates of row i = i0 + mq*32 + il
        const u32 codebase = (u32)(jt << 4);
        const bool diag = (jt == diag_jt) && (mq == nq);
        #pragma unroll
        for (int rg = 0; rg < 16; ++rg) {
            const u32 u = __float_as_uint(acc[rg]);
            const u32 mono = u ^ ((u32)(((int)u) >> 31) | 0x80000000u); // order-preserving
            u32 key = (mono & 0xFFFFFF00u) | (codebase + (u32)rg);
            if (diag && ((rg & 3) + 8 * (rg >> 2) + 4 * half == il)) key = 0u; // kill self
            u32 t = key;
            #pragma unroll
            for (int c = 0; c < CAND; ++c) {        // branchless sorted insert (desc)
                const u32 hi = umax32(keys[c], t);
                t = umin32(keys[c], t);
                keys[c] = hi;
            }
        }
    }

    // publish per-slot sorted candidate lists
    {
        const int r = mq * 32 + il;
        const int s = nq * 2 + half;
        u32* dst = keysL + (r * 4 + s) * CAND;
        #pragma unroll
        for (int c = 0; c < CAND; ++c) dst[c] = keys[c];
    }
    __syncthreads();

    // 4-way merge of sorted key lists -> top-12 per row, decode j from code byte
    if (tid < 64) {
        const u32* kl = keysL + tid * (4 * CAND);
        int p0 = 0, p1 = 0, p2 = 0, p3 = 0;
        #pragma unroll
        for (int o = 0; o < CAND; ++o) {
            const u32 k0v = kl[p0];
            const u32 k1v = kl[CAND + p1];
            const u32 k2v = kl[2 * CAND + p2];
            const u32 k3v = kl[3 * CAND + p3];
            int bg = 0; u32 bv = k0v;
            if (k1v > bv) { bv = k1v; bg = 1; }
            if (k2v > bv) { bv = k2v; bg = 2; }
            if (k3v > bv) { bv = k3v; bg = 3; }
            const int code = (int)(bv & 0xFFu);
            const int jtv = code >> 4, rg = code & 15;
            // j = jt*64 + nq*32 + (rg&3)+8*(rg>>2)+4*half, slot s=bg: nq=s>>1, half=s&1
            mj[tid * CAND + o] = jtv * 64 + (bg >> 1) * 32 + (rg & 3) + 8 * (rg >> 2)
                                 + 4 * (bg & 1);
            p0 += (bg == 0); p1 += (bg == 1); p2 += (bg == 2); p3 += (bg == 3);
        }
    }
    __syncthreads();

    // fp64 rescore, parallel over 3 groups of 4 candidates (dv aliases dead tiles)
    const float*  tokB = tok  + (size_t)b * N_ * D_;
    const double* invB = invn + b * N_;
    if (tid < 192) {
        const int r = tid & 63, g = tid >> 6;
        const int gi = i0 + r;
        const float* qi = tokB + (size_t)gi * D_;
        const double di = invB[gi];
        #pragma unroll 1
        for (int cc = 0; cc < 4; ++cc) {
            const int c = g * 4 + cc;
            const int j = mj[r * CAND + c];
            const float* qj = tokB + (size_t)j * D_;
            double s = 0.0;
            for (int d = 0; d < D_; d += 4) {
                const float4 x = *reinterpret_cast<const float4*>(qi + d);
                const float4 y = *reinterpret_cast<const float4*>(qj + d);
                s += (double)x.x * y.x + (double)x.y * y.y +
                     (double)x.z * y.z + (double)x.w * y.w;
            }
            dv[r * CAND + c] = s * di * invB[j];
        }
    }
    __syncthreads();

    // exact top-8 by fp64 rank (ties -> lower index, matching lax.top_k)
    if (tid < 64) {
        const int out_base = (b * N_ + i0 + tid) * K_;
        #pragma unroll 1
        for (int c = 0; c < CAND; ++c) {
            const double dc = dv[tid * CAND + c]; const int jc = mj[tid * CAND + c];
            int rank = 0;
            #pragma unroll 1
            for (int c2 = 0; c2 < CAND; ++c2) {
                if (c2 == c) continue;
                const double d2 = dv[tid * CAND + c2]; const int j2 = mj[tid * CAND + c2];
                if (d2 > dc || (d2 == dc && j2 < jc)) ++rank;
            }
            if (rank < K_) topk[out_base + rank] = jc;
        }
    }
}

// ------------- Kernel 3: mutual filter + scatter 1.0 -------------
__global__ __launch_bounds__(256) void mutual_kernel(const int* __restrict__ topk,
                                                     float* __restrict__ out) {
    const int gid = blockIdx.x * 256 + threadIdx.x;   // 32768*8 threads
    const int row = gid >> 3, s = gid & 7;
    const int j = topk[row * K_ + s];
    const int i = row & (N_ - 1);
    const int* tj = topk + ((row & ~(N_ - 1)) + j) * K_;
    bool m = false;
    #pragma unroll
    for (int u = 0; u < K_; ++u) m = m || (tj[u] == i);
    if (m) out[(size_t)row * N_ + j] = 1.0f;
}

extern "C" void kernel_launch(void* const* d_in, const int* in_sizes, int n_in,
                              void* d_out, int out_size, void* d_ws, size_t ws_size,
                              hipStream_t stream) {
    const float* tok = (const float*)d_in[0];
    float* out = (float*)d_out;
    double* invn = (double*)d_ws;                                  // 256 KB
    int* topk = (int*)((char*)d_ws + (size_t)B_ * N_ * sizeof(double)); // 1 MB
    // bf16 hi/lo scratch lives in d_out (32 MB of 128 MB) until memset
    u16* xhi = (u16*)d_out;
    u16* xlo = xhi + (size_t)B_ * N_ * D_;

    prep_kernel<<<dim3(B_ * N_ / 4), 256, 0, stream>>>(tok, invn, xhi, xlo);
    sim_topk_kernel<<<dim3(512), 256, 0, stream>>>(xhi, xlo, tok, invn, topk);
    hipMemsetAsync(d_out, 0, (size_t)out_size * sizeof(float), stream);
    mutual_kernel<<<dim3(B_ * N_ * K_ / 256), 256, 0, stream>>>(topk, out);
}

// Round 2
// 325.386 us; speedup vs baseline: 1.7727x; 1.0380x over previous
//
#include <hip/hip_runtime.h>
#include <math.h>
#include <stdint.h>

#define B_ 32
#define N_ 1024
#define D_ 256
#define K_ 8
#define CAND 12

typedef unsigned short u16;
typedef unsigned int u32;
typedef __attribute__((ext_vector_type(8))) short s16x8;   // 8 bf16 (4 VGPRs)
typedef __attribute__((ext_vector_type(16))) float f32x16; // 32x32 accumulator

__device__ inline void cp16(const void* g, void* l) {
    // async global->LDS, 16B/lane; LDS dest = wave-uniform base + lane*16
    __builtin_amdgcn_global_load_lds((const __attribute__((address_space(1))) void*)g,
                                     (__attribute__((address_space(3))) void*)l, 16, 0, 0);
}

__device__ inline u16 f2bf(float f) {               // RNE float->bf16 bits
    uint32_t u = __float_as_uint(f);
    return (u16)((u + 0x7fffu + ((u >> 16) & 1u)) >> 16);
}
__device__ inline float bf2f(u16 h) { return __uint_as_float(((uint32_t)h) << 16); }
__device__ inline u32 umax32(u32 a, u32 b) { return a > b ? a : b; }
__device__ inline u32 umin32(u32 a, u32 b) { return a < b ? a : b; }

// ------------- Kernel 1: fp64 inverse norms + normalized bf16 hi/lo -------------
__global__ __launch_bounds__(256) void prep_kernel(const float* __restrict__ tok,
                                                   double* __restrict__ invn,
                                                   u16* __restrict__ xhi,
                                                   u16* __restrict__ xlo) {
    const int tid = threadIdx.x;
    const int wave = tid >> 6, lane = tid & 63;
    const int row = blockIdx.x * 4 + wave;          // 32768 rows
    const float4 v = *reinterpret_cast<const float4*>(tok + (size_t)row * D_ + lane * 4);
    double s = (double)v.x * v.x + (double)v.y * v.y +
               (double)v.z * v.z + (double)v.w * v.w;
    #pragma unroll
    for (int off = 32; off > 0; off >>= 1) s += __shfl_xor(s, off, 64);
    const double inv = 1.0 / (sqrt(s) + 1e-8);
    if (lane == 0) invn[row] = inv;
    const float x0 = (float)(v.x * inv), x1 = (float)(v.y * inv),
                x2 = (float)(v.z * inv), x3 = (float)(v.w * inv);
    ushort4 h, l;
    h.x = f2bf(x0); l.x = f2bf(x0 - bf2f(h.x));
    h.y = f2bf(x1); l.y = f2bf(x1 - bf2f(h.y));
    h.z = f2bf(x2); l.z = f2bf(x2 - bf2f(h.z));
    h.w = f2bf(x3); l.w = f2bf(x3 - bf2f(h.w));
    *reinterpret_cast<ushort4*>(xhi + (size_t)row * D_ + lane * 4) = h;
    *reinterpret_cast<ushort4*>(xlo + (size_t)row * D_ + lane * 4) = l;
}

// ------------- Kernel 2: MFMA sim + in-register top-12 + fp64 rescore -------------
// R2 structure:
//  * A fragments (hi+lo, all 4 kc x 4 ks) cached in registers for the whole kernel
//    (loop-invariant across jt) -> per-round staging is B-only (16KB), LDS reads halved.
//  * 3-buffer, 2-round-ahead B pipeline: raw s_barrier + counted `s_waitcnt vmcnt(8)`
//    (4 cp16/wave/stage, 2 stages in flight; never drain to 0 in the loop).
//  * Swapped MFMA (mfma(B,A)): lane <-> i-row, reg <-> j; top-K scan is register-only
//    (packed u32 keys: 24-bit monotone fp32 | 8-bit (jt,reg) code, branchless
//    v_max/v_min insert chain) and overlaps the in-flight loads of the next jt.
// LDS carve (64512 B -> 2 blocks/CU, matching grid 512 = 2/CU):
//   [0,49152)      B tiles x3 bufs: each [Bh 8KB | Bl 8KB], rows [64][8x16B], XOR-swizzled
//   [49152,61440)  keysL [64 rows][4 slots][12] u32
//   [61440,64512)  mj [64][12] int
//   dv[64][12] double aliases tiles (dead after main loop)
__global__ __launch_bounds__(256, 2) void sim_topk_kernel(const u16* __restrict__ Xhi,
                                                          const u16* __restrict__ Xlo,
                                                          const float* __restrict__ tok,
                                                          const double* __restrict__ invn,
                                                          int* __restrict__ topk) {
    __shared__ __align__(16) char smem[64512];
    char* tiles = smem;
    u32*    keysL = (u32*)(smem + 49152);
    int*    mj    = (int*)(smem + 61440);
    double* dv    = (double*)smem;

    // XCD batch-affinity swizzle: each XCD owns 4 whole batches -> B panel L2-resident
    const int id    = blockIdx.x;            // 0..511
    const int chunk = id >> 3;               // 0..63
    const int b  = (id & 7) * 4 + (chunk >> 4);
    const int i0 = (chunk & 15) * 64;

    const int tid = threadIdx.x;
    const int w = tid >> 6, lane = tid & 63;
    const int mq = w >> 1, nq = w & 1;       // 2x2 wave grid of 32x32 tiles
    const int half = lane >> 5;
    const int il = lane & 31;

    const u16* XhiB = Xhi + (size_t)b * N_ * D_;
    const u16* XloB = Xlo + (size_t)b * N_ * D_;

    // staging role: wave 0/1 -> hi rows 0-31/32-63, wave 2/3 -> lo rows 0-31/32-63
    const int srr = lane >> 3, spp = lane & 7;       // row-in-group, chunk-pos
    const u16* ssrc = (w < 2) ? XhiB : XloB;
    const int  sgoff = (spp ^ srr) * 8;              // gathered source chunk (u16 units)
    const int  srow  = (w & 1) * 32 + srr;           // + t*8
    char* const sbase = tiles + ((w < 2) ? 0 : 8192) + (w & 1) * 4096;

    // fragment rows (fixed per lane)
    const int ra = mq * 32 + il;
    const int rb = nq * 32 + il;
    const int xa = ra & 7, xb = rb & 7;              // XOR keys

    // ---- prologue: load A fragments (hi+lo, 4kc x 4ks) into registers ----
    s16x8 Ahf[4][4], Alf[4][4];                      // 128 VGPRs, static-indexed only
    #pragma unroll
    for (int kc = 0; kc < 4; ++kc) {
        __syncthreads();                             // tiles free for overwrite
        #pragma unroll
        for (int t = 0; t < 4; ++t) {
            const int rr = srow + t * 8;
            cp16(ssrc + (size_t)(i0 + rr) * D_ + kc * 64 + sgoff, sbase + t * 1024);
        }
        __syncthreads();                             // vmcnt(0) drain ok in prologue
        #pragma unroll
        for (int ks = 0; ks < 4; ++ks) {
            const int ca = ((ks * 2 + half) ^ xa) * 16;
            Ahf[kc][ks] = *(const s16x8*)(tiles +        ra * 128 + ca);
            Alf[kc][ks] = *(const s16x8*)(tiles + 8192 + ra * 128 + ca);
        }
    }
    __syncthreads();                                 // A reads done; clean vmcnt slate

    auto STAGE_B = [&](int jtn, int kcn, int bufn) { // 4 cp16/wave = 4KB; 16KB total
        const int j0n = jtn * 64;
        char* bdst = sbase + bufn * 16384;
        #pragma unroll
        for (int t = 0; t < 4; ++t) {
            const int rr = srow + t * 8;
            cp16(ssrc + (size_t)(j0n + rr) * D_ + kcn * 64 + sgoff, bdst + t * 1024);
        }
    };

    const int diag_jt = i0 >> 6;                     // jt where j-tile == i-strip
    u32 keys[CAND];
    #pragma unroll
    for (int c = 0; c < CAND; ++c) keys[c] = 0u;     // real sims always pack > 0

    STAGE_B(0, 0, 0);
    STAGE_B(0, 1, 1);
    int cur = 0;

    for (int jt = 0; jt < 16; ++jt) {
        f32x16 acc;
        #pragma unroll
        for (int c = 0; c < 16; ++c) acc[c] = 0.0f;

        #pragma unroll
        for (int kc = 0; kc < 4; ++kc) {
            const int nxt = (cur == 2) ? 0 : cur + 1;
            const int n2  = (nxt == 2) ? 0 : nxt + 1;
            // issue stage for round r+2; wait for round r's loads (8 = 2 stages in flight)
            if (kc == 0) {
                STAGE_B(jt, 2, n2);
                asm volatile("s_waitcnt vmcnt(8)" ::: "memory");
            } else if (kc == 1) {
                STAGE_B(jt, 3, n2);
                asm volatile("s_waitcnt vmcnt(8)" ::: "memory");
            } else if (kc == 2) {
                if (jt < 15) {
                    STAGE_B(jt + 1, 0, n2);
                    asm volatile("s_waitcnt vmcnt(8)" ::: "memory");
                } else {
                    asm volatile("s_waitcnt vmcnt(4)" ::: "memory");
                }
            } else {
                if (jt < 15) {
                    STAGE_B(jt + 1, 1, n2);
                    asm volatile("s_waitcnt vmcnt(8)" ::: "memory");
                } else {
                    asm volatile("s_waitcnt vmcnt(0)" ::: "memory");
                }
            }
            __builtin_amdgcn_s_barrier();            // B1: all waves' round-r loads landed
            __builtin_amdgcn_sched_barrier(0);       // pin ds_reads below the barrier
            const char* bb = tiles + cur * 16384;
            #pragma unroll
            for (int ks = 0; ks < 4; ++ks) {
                const int cb = ((ks * 2 + half) ^ xb) * 16;
                const s16x8 bh = *(const s16x8*)(bb +        rb * 128 + cb);
                const s16x8 bl = *(const s16x8*)(bb + 8192 + rb * 128 + cb);
                acc = __builtin_amdgcn_mfma_f32_32x32x16_bf16(bh, Ahf[kc][ks], acc, 0, 0, 0);
                acc = __builtin_amdgcn_mfma_f32_32x32x16_bf16(bl, Ahf[kc][ks], acc, 0, 0, 0);
                acc = __builtin_amdgcn_mfma_f32_32x32x16_bf16(bh, Alf[kc][ks], acc, 0, 0, 0);
            }
            __builtin_amdgcn_sched_barrier(0);       // pin reads/MFMA above B2
            __builtin_amdgcn_s_barrier();            // B2: buf[cur] free for stage r+3
            cur = nxt;
        }

        // in-register scan (16 j-candidates of row i0+mq*32+il); overlaps next loads
        const u32 codebase = (u32)(jt << 4);
        const bool diag = (jt == diag_jt) && (mq == nq);
        #pragma unroll
        for (int rg = 0; rg < 16; ++rg) {
            const u32 u = __float_as_uint(acc[rg]);
            const u32 mono = u ^ ((u32)(((int)u) >> 31) | 0x80000000u); // order-preserving
            u32 key = (mono & 0xFFFFFF00u) | (codebase + (u32)rg);
            if (diag && ((rg & 3) + 8 * (rg >> 2) + 4 * half == il)) key = 0u; // kill self
            u32 t = key;
            #pragma unroll
            for (int c = 0; c < CAND; ++c) {         // branchless sorted insert (desc)
                const u32 hi = umax32(keys[c], t);
                t = umin32(keys[c], t);
                keys[c] = hi;
            }
        }
    }

    // publish per-slot sorted candidate lists
    {
        const int r = mq * 32 + il;
        const int s = nq * 2 + half;
        u32* dst = keysL + (r * 4 + s) * CAND;
        #pragma unroll
        for (int c = 0; c < CAND; ++c) dst[c] = keys[c];
    }
    __syncthreads();

    // 4-way merge of sorted key lists -> top-12 per row, decode j from code byte
    if (tid < 64) {
        const u32* kl = keysL + tid * (4 * CAND);
        int p0 = 0, p1 = 0, p2 = 0, p3 = 0;
        #pragma unroll
        for (int o = 0; o < CAND; ++o) {
            const u32 k0v = kl[p0];
            const u32 k1v = kl[CAND + p1];
            const u32 k2v = kl[2 * CAND + p2];
            const u32 k3v = kl[3 * CAND + p3];
            int bg = 0; u32 bv = k0v;
            if (k1v > bv) { bv = k1v; bg = 1; }
            if (k2v > bv) { bv = k2v; bg = 2; }
            if (k3v > bv) { bv = k3v; bg = 3; }
            const int code = (int)(bv & 0xFFu);
            const int jtv = code >> 4, rg = code & 15;
            // j = jt*64 + nq*32 + (rg&3)+8*(rg>>2)+4*half; slot bg: nq=bg>>1, half=bg&1
            mj[tid * CAND + o] = jtv * 64 + (bg >> 1) * 32 + (rg & 3) + 8 * (rg >> 2)
                                 + 4 * (bg & 1);
            p0 += (bg == 0); p1 += (bg == 1); p2 += (bg == 2); p3 += (bg == 3);
        }
    }
    __syncthreads();

    // fp64 rescore, parallel over 3 groups of 4 candidates (dv aliases dead tiles)
    const float*  tokB = tok  + (size_t)b * N_ * D_;
    const double* invB = invn + b * N_;
    if (tid < 192) {
        const int r = tid & 63, g = tid >> 6;
        const int gi = i0 + r;
        const float* qi = tokB + (size_t)gi * D_;
        const double di = invB[gi];
        #pragma unroll 1
        for (int cc = 0; cc < 4; ++cc) {
            const int c = g * 4 + cc;
            const int j = mj[r * CAND + c];
            const float* qj = tokB + (size_t)j * D_;
            double s = 0.0;
            for (int d = 0; d < D_; d += 4) {
                const float4 x = *reinterpret_cast<const float4*>(qi + d);
                const float4 y = *reinterpret_cast<const float4*>(qj + d);
                s += (double)x.x * y.x + (double)x.y * y.y +
                     (double)x.z * y.z + (double)x.w * y.w;
            }
            dv[r * CAND + c] = s * di * invB[j];
        }
    }
    __syncthreads();

    // exact top-8 by fp64 rank (ties -> lower index, matching lax.top_k)
    if (tid < 64) {
        const int out_base = (b * N_ + i0 + tid) * K_;
        #pragma unroll 1
        for (int c = 0; c < CAND; ++c) {
            const double dc = dv[tid * CAND + c]; const int jc = mj[tid * CAND + c];
            int rank = 0;
            #pragma unroll 1
            for (int c2 = 0; c2 < CAND; ++c2) {
                if (c2 == c) continue;
                const double d2 = dv[tid * CAND + c2]; const int j2 = mj[tid * CAND + c2];
                if (d2 > dc || (d2 == dc && j2 < jc)) ++rank;
            }
            if (rank < K_) topk[out_base + rank] = jc;
        }
    }
}

// ------------- Kernel 3: mutual filter + scatter 1.0 -------------
__global__ __launch_bounds__(256) void mutual_kernel(const int* __restrict__ topk,
                                                     float* __restrict__ out) {
    const int gid = blockIdx.x * 256 + threadIdx.x;   // 32768*8 threads
    const int row = gid >> 3, s = gid & 7;
    const int j = topk[row * K_ + s];
    const int i = row & (N_ - 1);
    const int* tj = topk + ((row & ~(N_ - 1)) + j) * K_;
    bool m = false;
    #pragma unroll
    for (int u = 0; u < K_; ++u) m = m || (tj[u] == i);
    if (m) out[(size_t)row * N_ + j] = 1.0f;
}

extern "C" void kernel_launch(void* const* d_in, const int* in_sizes, int n_in,
                              void* d_out, int out_size, void* d_ws, size_t ws_size,
                              hipStream_t stream) {
    const float* tok = (const float*)d_in[0];
    float* out = (float*)d_out;
    double* invn = (double*)d_ws;                                  // 256 KB
    int* topk = (int*)((char*)d_ws + (size_t)B_ * N_ * sizeof(double)); // 1 MB
    // bf16 hi/lo scratch lives in d_out (32 MB of 128 MB) until memset
    u16* xhi = (u16*)d_out;
    u16* xlo = xhi + (size_t)B_ * N_ * D_;

    prep_kernel<<<dim3(B_ * N_ / 4), 256, 0, stream>>>(tok, invn, xhi, xlo);
    sim_topk_kernel<<<dim3(512), 256, 0, stream>>>(xhi, xlo, tok, invn, topk);
    hipMemsetAsync(d_out, 0, (size_t)out_size * sizeof(float), stream);
    mutual_kernel<<<dim3(B_ * N_ * K_ / 256), 256, 0, stream>>>(topk, out);
}